// Round 5
// baseline (966.512 us; speedup 1.0000x reference)
//
#include <hip/hip_runtime.h>
#include <float.h>

#define N_NODES   50000
#define N_EDGES   800000
#define INDIM1    128
#define HC        64
#define N_GRAPHS  64
#define NEG_SLOPE 0.2f
#define CAP       64      // max in-degree slot capacity; deg~Poisson(16), P(>64)<1e-20

// ---------------- fused CSR-build (scatter) + layer-1 transform ----------------
// Interleave 2:1 scatter:transform by blockIdx%3 so latency-bound scatter waves
// and VALU-bound transform waves co-schedule on each CU.
// Scatter: pos = dst*CAP + cursor++  (no hist/scan needed at all).
// Transform: W read via L1 (32KB, coalesced row loads), 4-node register
// blocking amortizes W traffic; only 8KB LDS so scatter occupancy stays high.
template <int INDIM, int NPW>
__global__ __launch_bounds__(256) void fused_build_transform(
    const int* __restrict__ src, const int* __restrict__ dst,
    const float* __restrict__ eattr, int* __restrict__ cursor,
    int2* __restrict__ csr_se,
    const float* __restrict__ x, const float* __restrict__ W,
    const float* __restrict__ att_s, const float* __restrict__ att_d,
    float* __restrict__ xs, float* __restrict__ a_src, float* __restrict__ a_dst)
{
    constexpr int K4 = INDIM / 4;
    __shared__ float4 xsh[4][4][K4];   // [wave][node-in-group][k4] : 8KB @ INDIM=128
    int i = blockIdx.x;
    int r = i % 3;
    if (r != 0) {
        // ---- scatter role ----
        int s = (i / 3) * 2 + (r - 1);
        int e = s * 256 + threadIdx.x;
        if (e < N_EDGES) {
            int d = dst[e];
            int c = atomicAdd(&cursor[d], 1);
            if (c < CAP)
                csr_se[(size_t)d * CAP + c] = make_int2(src[e], __float_as_int(eattr[e]));
        }
        return;
    }
    // ---- transform role ----
    int b = i / 3;
    int t = threadIdx.x;
    int w = t >> 6, lane = t & 63;
    float avs = att_s[lane], avd = att_d[lane];
    int node0 = b * (4 * NPW) + w * NPW;
    for (int ng = 0; ng < NPW; ng += 4) {
        int nbase = node0 + ng;
        if (nbase >= N_NODES) return;     // wave-uniform
        for (int q = lane; q < 4 * K4; q += 64) {
            int nn = q / K4, kk = q - nn * K4;
            int node = nbase + nn;
            xsh[w][nn][kk] = (node < N_NODES)
                ? ((const float4*)(x + (size_t)node * INDIM))[kk]
                : make_float4(0.f, 0.f, 0.f, 0.f);
        }
        float acc[4] = {0.f, 0.f, 0.f, 0.f};
#pragma unroll
        for (int k4 = 0; k4 < K4; ++k4) {
            float w0 = W[(4 * k4 + 0) * 64 + lane];
            float w1 = W[(4 * k4 + 1) * 64 + lane];
            float w2 = W[(4 * k4 + 2) * 64 + lane];
            float w3 = W[(4 * k4 + 3) * 64 + lane];
#pragma unroll
            for (int nn = 0; nn < 4; ++nn) {
                float4 xv = xsh[w][nn][k4];
                acc[nn] = fmaf(xv.x, w0, acc[nn]);
                acc[nn] = fmaf(xv.y, w1, acc[nn]);
                acc[nn] = fmaf(xv.z, w2, acc[nn]);
                acc[nn] = fmaf(xv.w, w3, acc[nn]);
            }
        }
#pragma unroll
        for (int nn = 0; nn < 4; ++nn) {
            int node = nbase + nn;
            if (node >= N_NODES) break;
            float a = acc[nn];
            xs[(size_t)node * 64 + lane] = a;
            float ps = a * avs;
            float pd = a * avd;
            for (int off = 1; off < 16; off <<= 1) {
                ps += __shfl_xor(ps, off);
                pd += __shfl_xor(pd, off);
            }
            if ((lane & 15) == 0) {
                a_src[node * 4 + (lane >> 4)] = ps;
                a_dst[node * 4 + (lane >> 4)] = pd;
            }
        }
    }
}

// ---------------- standalone transform (layer 2) ----------------
template <int INDIM, int NPW>
__global__ __launch_bounds__(256) void transform_kernel(const float* __restrict__ x,
                                                        const float* __restrict__ W,
                                                        const float* __restrict__ att_s,
                                                        const float* __restrict__ att_d,
                                                        float* __restrict__ xs,
                                                        float* __restrict__ a_src,
                                                        float* __restrict__ a_dst) {
    constexpr int K4 = INDIM / 4;
    __shared__ float4 Wsh[K4 * 64];     // [k4][col]
    __shared__ float4 xsh[4][K4];
    int t = threadIdx.x;
    for (int i = t; i < K4 * 64; i += 256) {
        int k4 = i >> 6, col = i & 63;
        Wsh[i] = make_float4(W[(4 * k4 + 0) * 64 + col], W[(4 * k4 + 1) * 64 + col],
                             W[(4 * k4 + 2) * 64 + col], W[(4 * k4 + 3) * 64 + col]);
    }
    __syncthreads();
    int w = t >> 6, lane = t & 63;
    float avs = att_s[lane], avd = att_d[lane];
    int node0 = blockIdx.x * (4 * NPW) + w * NPW;
    for (int ni = 0; ni < NPW; ++ni) {
        int node = node0 + ni;
        if (node >= N_NODES) return;   // wave-uniform
        if (lane < K4) xsh[w][lane] = ((const float4*)(x + (size_t)node * INDIM))[lane];
        float acc = 0.f;
#pragma unroll
        for (int k4 = 0; k4 < K4; ++k4) {
            float4 xv = xsh[w][k4];
            float4 wv = Wsh[k4 * 64 + lane];
            acc = fmaf(xv.x, wv.x, acc);
            acc = fmaf(xv.y, wv.y, acc);
            acc = fmaf(xv.z, wv.z, acc);
            acc = fmaf(xv.w, wv.w, acc);
        }
        xs[(size_t)node * 64 + lane] = acc;
        float ps = acc * avs;
        float pd = acc * avd;
        for (int off = 1; off < 16; off <<= 1) {
            ps += __shfl_xor(ps, off);
            pd += __shfl_xor(pd, off);
        }
        if ((lane & 15) == 0) {
            a_src[node * 4 + (lane >> 4)] = ps;
            a_dst[node * 4 + (lane >> 4)] = pd;
        }
    }
}

// ---------------- fused attention + aggregation ----------------
// One wave per node, 16-edge chunks, fully in-register alpha + online softmax.
// mode 1: relu, write hbuf (layer 1).  mode 0: atomicAdd into pooled out (layer 2).
__global__ __launch_bounds__(256) void aggregate_kernel(const float* __restrict__ xs,
                                                        const int2* __restrict__ csr_se,
                                                        const int* __restrict__ degp,
                                                        const float* __restrict__ a_src,
                                                        const float* __restrict__ a_dst,
                                                        const float* __restrict__ We,
                                                        const float* __restrict__ ae,
                                                        const float* __restrict__ bias,
                                                        const int* __restrict__ batch,
                                                        float* __restrict__ outb,
                                                        int mode) {
    int w = threadIdx.x >> 6, lane = threadIdx.x & 63;
    int node = blockIdx.x * 4 + w;
    if (node >= N_NODES) return;
    const int e_idx = lane >> 2;   // 0..15: edge slot in chunk
    const int h4 = lane & 3;       // head for the softmax lanes
    const int h2 = lane >> 4;      // my output head (channel = lane & 15)

    // wd[h] = dot(We[h*16..], ae[h]) computed inline (8 VALU ops, no extra kernel)
    float p = We[lane] * ae[lane];
    p += __shfl_xor(p, 1); p += __shfl_xor(p, 2);
    p += __shfl_xor(p, 4); p += __shfl_xor(p, 8);   // lane holds wd[lane>>4]
    float wdv = __shfl(p, h4 << 4);                 // wd[h4]

    int beg = node * CAP;
    int end = beg + min(degp[node], CAP);
    float adv = a_dst[node * 4 + h4];

    float m = -FLT_MAX;            // running max, head h4
    float s = 0.f;                 // partial weight sum (this lane's slots)
    float acc = 0.f;               // output accumulator, head h2

    for (int j0 = beg; j0 < end; j0 += 16) {
        int j = j0 + e_idx;
        bool v = (j < end);
        int sv = 0;
        float a = -FLT_MAX;
        if (v) {
            int2 se = csr_se[j];
            sv = se.x;
            float ea = __int_as_float(se.y);
            float as = a_src[sv * 4 + h4];          // gather, L2-resident (800KB)
            a = as + adv + ea * wdv;
            a = a > 0.f ? a : NEG_SLOPE * a;
        }
        float cm = a;
        cm = fmaxf(cm, __shfl_xor(cm, 4));
        cm = fmaxf(cm, __shfl_xor(cm, 8));
        cm = fmaxf(cm, __shfl_xor(cm, 16));
        cm = fmaxf(cm, __shfl_xor(cm, 32));
        float mn = fmaxf(m, cm);
        float sc = __expf(m - mn);                  // rescale old state
        float wgt = __expf(a - mn);                 // 0 for invalid slots
        s = s * sc + wgt;
        m = mn;
        acc *= __shfl(sc, h2);
#pragma unroll
        for (int e = 0; e < 16; ++e) {
            float wg = __shfl(wgt, (e << 2) | h2);
            int svb = __shfl(sv, e << 2);
            acc = fmaf(wg, xs[(size_t)svb * 64 + lane], acc);
        }
    }
    s += __shfl_xor(s, 4);
    s += __shfl_xor(s, 8);
    s += __shfl_xor(s, 16);
    s += __shfl_xor(s, 32);
    float sh = __shfl(s, h2);
    float res = (sh > 0.f) ? acc / sh : 0.f;
    res += bias[lane];
    if (mode == 1) {
        res = fmaxf(res, 0.f);
        outb[(size_t)node * 64 + lane] = res;
    } else {
        int g = batch[node];
        atomicAdd(&outb[g * 64 + lane], res);       // direct pooled sum
    }
}

// Divide pooled sums by per-graph node counts (binary search on sorted batch).
__global__ void pool_div_kernel(float* __restrict__ out, const int* __restrict__ batch) {
    int g = blockIdx.x, t = threadIdx.x;
    int lo = 0, hi = N_NODES;
    while (lo < hi) { int mid = (lo + hi) >> 1; if (batch[mid] < g) lo = mid + 1; else hi = mid; }
    int lo2 = lo, hi2 = N_NODES;
    while (lo2 < hi2) { int mid = (lo2 + hi2) >> 1; if (batch[mid] <= g) lo2 = mid + 1; else hi2 = mid; }
    float c = (float)max(lo2 - lo, 1);
    out[g * 64 + t] /= c;
}

// ---------------- launch ----------------

extern "C" void kernel_launch(void* const* d_in, const int* in_sizes, int n_in,
                              void* d_out, int out_size, void* d_ws, size_t ws_size,
                              hipStream_t stream) {
    const float* x    = (const float*)d_in[0];
    const int*   eidx = (const int*)d_in[1];
    const float* eat  = (const float*)d_in[2];
    const int*   batch= (const int*)d_in[3];
    const float* W1   = (const float*)d_in[4];
    const float* We1  = (const float*)d_in[5];
    const float* as1  = (const float*)d_in[6];
    const float* ad1  = (const float*)d_in[7];
    const float* ae1  = (const float*)d_in[8];
    const float* b1   = (const float*)d_in[9];
    const float* W2   = (const float*)d_in[10];
    const float* We2  = (const float*)d_in[11];
    const float* as2  = (const float*)d_in[12];
    const float* ad2  = (const float*)d_in[13];
    const float* ae2  = (const float*)d_in[14];
    const float* b2   = (const float*)d_in[15];
    const int* src  = eidx;             // edge_index[0]
    const int* dstp = eidx + N_EDGES;   // edge_index[1]
    float* out = (float*)d_out;

    char* p = (char*)d_ws;
    auto alloc = [&](size_t bytes) {
        char* r = p;
        p += (bytes + 255) & ~(size_t)255;
        return r;
    };
    int2*  csrse  = (int2*)alloc((size_t)N_NODES * CAP * 8);   // 25.6 MB
    float* xs     = (float*)alloc((size_t)N_NODES * 64 * 4);
    float* hbuf   = (float*)alloc((size_t)N_NODES * 64 * 4);
    float* asrc   = (float*)alloc((size_t)N_NODES * 4 * 4);
    float* adst   = (float*)alloc((size_t)N_NODES * 4 * 4);
    int*   cursor = (int*)alloc((size_t)N_NODES * 4);

    hipMemsetAsync(cursor, 0, (size_t)N_NODES * 4, stream);
    hipMemsetAsync(d_out, 0, (size_t)N_GRAPHS * 64 * 4, stream);

    const int NPW = 8;
    const int TB = (N_NODES + 4 * NPW - 1) / (4 * NPW);   // 1563
    const int NB = (N_NODES + 3) / 4;                      // aggregate blocks

    // fused scatter (2 of 3 blocks) + transform1 (1 of 3) : grid = 3*TB covers
    // scatter indices 0..2*TB+1 > EB=3125 (bounds-checked inside)
    fused_build_transform<INDIM1, NPW><<<3 * TB, 256, 0, stream>>>(
        src, dstp, eat, cursor, csrse, x, W1, as1, ad1, xs, asrc, adst);

    // layer 1 attention+aggregate -> hbuf (relu)
    aggregate_kernel<<<NB, 256, 0, stream>>>(xs, csrse, cursor, asrc, adst,
                                             We1, ae1, b1, batch, hbuf, 1);
    // layer 2 transform
    transform_kernel<HC, NPW><<<TB, 256, 0, stream>>>(hbuf, W2, as2, ad2, xs, asrc, adst);
    // layer 2 attention+aggregate -> pooled atomic sums in d_out
    aggregate_kernel<<<NB, 256, 0, stream>>>(xs, csrse, cursor, asrc, adst,
                                             We2, ae2, b2, batch, out, 0);
    // divide by per-graph counts
    pool_div_kernel<<<N_GRAPHS, 64, 0, stream>>>(out, batch);
}

// Round 6
// 354.770 us; speedup vs baseline: 2.7243x; 2.7243x over previous
//
#include <hip/hip_runtime.h>
#include <float.h>

#define N_NODES   50000
#define N_EDGES   800000
#define INDIM1    128
#define HC        64
#define N_GRAPHS  64
#define NEG_SLOPE 0.2f
#define CAP       64      // slot capacity/node; deg~Poisson(16); validated absmax=0 in R5

// ---------------- CSR build: one kernel, fixed-capacity slots ----------------
// pos = dst*CAP + cursor[dst]++ ; cursor doubles as deg afterwards.
// (R5 validated: no node exceeds CAP on this input.)
__global__ __launch_bounds__(256) void scatter_kernel(const int* __restrict__ src,
                                                      const int* __restrict__ dst,
                                                      const float* __restrict__ eattr,
                                                      int* __restrict__ cursor,
                                                      int2* __restrict__ csr_se) {
    int e = blockIdx.x * blockDim.x + threadIdx.x;
    if (e < N_EDGES) {
        int d = dst[e];
        int c = atomicAdd(&cursor[d], 1);
        if (c < CAP)
            csr_se[(size_t)d * CAP + c] = make_int2(src[e], __float_as_int(eattr[e]));
    }
}

// ---------------- node transform (LDS-staged W — R4-proven shape) ----------------
template <int INDIM, int NPW>
__global__ __launch_bounds__(256) void transform_kernel(const float* __restrict__ x,
                                                        const float* __restrict__ W,
                                                        const float* __restrict__ att_s,
                                                        const float* __restrict__ att_d,
                                                        float* __restrict__ xs,
                                                        float* __restrict__ a_src,
                                                        float* __restrict__ a_dst) {
    constexpr int K4 = INDIM / 4;
    __shared__ float4 Wsh[K4 * 64];     // [k4][col]
    __shared__ float4 xsh[4][K4];
    int t = threadIdx.x;
    for (int i = t; i < K4 * 64; i += 256) {
        int k4 = i >> 6, col = i & 63;
        Wsh[i] = make_float4(W[(4 * k4 + 0) * 64 + col], W[(4 * k4 + 1) * 64 + col],
                             W[(4 * k4 + 2) * 64 + col], W[(4 * k4 + 3) * 64 + col]);
    }
    __syncthreads();
    int w = t >> 6, lane = t & 63;
    float avs = att_s[lane], avd = att_d[lane];
    int node0 = blockIdx.x * (4 * NPW) + w * NPW;
    for (int ni = 0; ni < NPW; ++ni) {
        int node = node0 + ni;
        if (node >= N_NODES) return;   // wave-uniform
        if (lane < K4) xsh[w][lane] = ((const float4*)(x + (size_t)node * INDIM))[lane];
        float acc = 0.f;
#pragma unroll
        for (int k4 = 0; k4 < K4; ++k4) {
            float4 xv = xsh[w][k4];
            float4 wv = Wsh[k4 * 64 + lane];
            acc = fmaf(xv.x, wv.x, acc);
            acc = fmaf(xv.y, wv.y, acc);
            acc = fmaf(xv.z, wv.z, acc);
            acc = fmaf(xv.w, wv.w, acc);
        }
        xs[(size_t)node * 64 + lane] = acc;
        float ps = acc * avs;
        float pd = acc * avd;
        for (int off = 1; off < 16; off <<= 1) {
            ps += __shfl_xor(ps, off);
            pd += __shfl_xor(pd, off);
        }
        if ((lane & 15) == 0) {
            a_src[node * 4 + (lane >> 4)] = ps;
            a_dst[node * 4 + (lane >> 4)] = pd;
        }
    }
}

// ---------------- fused attention + aggregation ----------------
// One wave per node, 16-edge chunks, in-register alpha + online softmax.
// mode 1: relu, write hbuf (layer 1).  mode 0: atomicAdd pooled sums (layer 2).
__global__ __launch_bounds__(256) void aggregate_kernel(const float* __restrict__ xs,
                                                        const int2* __restrict__ csr_se,
                                                        const int* __restrict__ degp,
                                                        const float* __restrict__ a_src,
                                                        const float* __restrict__ a_dst,
                                                        const float* __restrict__ We,
                                                        const float* __restrict__ ae,
                                                        const float* __restrict__ bias,
                                                        const int* __restrict__ batch,
                                                        float* __restrict__ outb,
                                                        int mode) {
    int w = threadIdx.x >> 6, lane = threadIdx.x & 63;
    int node = blockIdx.x * 4 + w;
    if (node >= N_NODES) return;
    const int e_idx = lane >> 2;   // 0..15: edge slot in chunk
    const int h4 = lane & 3;       // head for softmax lanes
    const int h2 = lane >> 4;      // my output head (channel = lane & 15)

    // wd[h] = dot(We[h*16..], ae[h]) inline (no extra kernel)
    float p = We[lane] * ae[lane];
    p += __shfl_xor(p, 1); p += __shfl_xor(p, 2);
    p += __shfl_xor(p, 4); p += __shfl_xor(p, 8);
    float wdv = __shfl(p, h4 << 4);                 // wd[h4]

    int beg = node * CAP;
    int end = beg + min(degp[node], CAP);
    float adv = a_dst[node * 4 + h4];

    float m = -FLT_MAX;
    float s = 0.f;
    float acc = 0.f;

    for (int j0 = beg; j0 < end; j0 += 16) {
        int j = j0 + e_idx;
        bool v = (j < end);
        int sv = 0;
        float a = -FLT_MAX;
        if (v) {
            int2 se = csr_se[j];
            sv = se.x;
            float ea = __int_as_float(se.y);
            float as = a_src[sv * 4 + h4];          // gather, 800KB L2-resident
            a = as + adv + ea * wdv;
            a = a > 0.f ? a : NEG_SLOPE * a;
        }
        float cm = a;
        cm = fmaxf(cm, __shfl_xor(cm, 4));
        cm = fmaxf(cm, __shfl_xor(cm, 8));
        cm = fmaxf(cm, __shfl_xor(cm, 16));
        cm = fmaxf(cm, __shfl_xor(cm, 32));
        float mn = fmaxf(m, cm);
        float sc = __expf(m - mn);
        float wgt = __expf(a - mn);                 // 0 for invalid slots
        s = s * sc + wgt;
        m = mn;
        acc *= __shfl(sc, h2);
#pragma unroll
        for (int e = 0; e < 16; ++e) {
            float wg = __shfl(wgt, (e << 2) | h2);
            int svb = __shfl(sv, e << 2);
            acc = fmaf(wg, xs[(size_t)svb * 64 + lane], acc);
        }
    }
    s += __shfl_xor(s, 4);
    s += __shfl_xor(s, 8);
    s += __shfl_xor(s, 16);
    s += __shfl_xor(s, 32);
    float sh = __shfl(s, h2);
    float res = (sh > 0.f) ? acc / sh : 0.f;
    res += bias[lane];
    if (mode == 1) {
        res = fmaxf(res, 0.f);
        outb[(size_t)node * 64 + lane] = res;
    } else {
        int g = batch[node];
        atomicAdd(&outb[g * 64 + lane], res);       // direct pooled sum
    }
}

// Divide pooled sums by per-graph node counts (binary search on sorted batch).
__global__ void pool_div_kernel(float* __restrict__ out, const int* __restrict__ batch) {
    int g = blockIdx.x, t = threadIdx.x;
    int lo = 0, hi = N_NODES;
    while (lo < hi) { int mid = (lo + hi) >> 1; if (batch[mid] < g) lo = mid + 1; else hi = mid; }
    int lo2 = lo, hi2 = N_NODES;
    while (lo2 < hi2) { int mid = (lo2 + hi2) >> 1; if (batch[mid] <= g) lo2 = mid + 1; else hi2 = mid; }
    float c = (float)max(lo2 - lo, 1);
    out[g * 64 + t] /= c;
}

// ---------------- launch ----------------

extern "C" void kernel_launch(void* const* d_in, const int* in_sizes, int n_in,
                              void* d_out, int out_size, void* d_ws, size_t ws_size,
                              hipStream_t stream) {
    const float* x    = (const float*)d_in[0];
    const int*   eidx = (const int*)d_in[1];
    const float* eat  = (const float*)d_in[2];
    const int*   batch= (const int*)d_in[3];
    const float* W1   = (const float*)d_in[4];
    const float* We1  = (const float*)d_in[5];
    const float* as1  = (const float*)d_in[6];
    const float* ad1  = (const float*)d_in[7];
    const float* ae1  = (const float*)d_in[8];
    const float* b1   = (const float*)d_in[9];
    const float* W2   = (const float*)d_in[10];
    const float* We2  = (const float*)d_in[11];
    const float* as2  = (const float*)d_in[12];
    const float* ad2  = (const float*)d_in[13];
    const float* ae2  = (const float*)d_in[14];
    const float* b2   = (const float*)d_in[15];
    const int* src  = eidx;             // edge_index[0]
    const int* dstp = eidx + N_EDGES;   // edge_index[1]
    float* out = (float*)d_out;

    char* p = (char*)d_ws;
    auto alloc = [&](size_t bytes) {
        char* r = p;
        p += (bytes + 255) & ~(size_t)255;
        return r;
    };
    int2*  csrse  = (int2*)alloc((size_t)N_NODES * CAP * 8);   // 25.6 MB
    float* xs     = (float*)alloc((size_t)N_NODES * 64 * 4);
    float* hbuf   = (float*)alloc((size_t)N_NODES * 64 * 4);
    float* asrc   = (float*)alloc((size_t)N_NODES * 4 * 4);
    float* adst   = (float*)alloc((size_t)N_NODES * 4 * 4);
    int*   cursor = (int*)alloc((size_t)N_NODES * 4);

    hipMemsetAsync(cursor, 0, (size_t)N_NODES * 4, stream);
    hipMemsetAsync(d_out, 0, (size_t)N_GRAPHS * 64 * 4, stream);

    const int EB = (N_EDGES + 255) / 256;                  // 3125
    const int NPW = 8;
    const int TB = (N_NODES + 4 * NPW - 1) / (4 * NPW);    // 1563
    const int NB = (N_NODES + 3) / 4;                      // 12500

    scatter_kernel<<<EB, 256, 0, stream>>>(src, dstp, eat, cursor, csrse);

    // layer 1
    transform_kernel<INDIM1, NPW><<<TB, 256, 0, stream>>>(x, W1, as1, ad1, xs, asrc, adst);
    aggregate_kernel<<<NB, 256, 0, stream>>>(xs, csrse, cursor, asrc, adst,
                                             We1, ae1, b1, batch, hbuf, 1);
    // layer 2
    transform_kernel<HC, NPW><<<TB, 256, 0, stream>>>(hbuf, W2, as2, ad2, xs, asrc, adst);
    aggregate_kernel<<<NB, 256, 0, stream>>>(xs, csrse, cursor, asrc, adst,
                                             We2, ae2, b2, batch, out, 0);
    // mean = sum / count
    pool_div_kernel<<<N_GRAPHS, 64, 0, stream>>>(out, batch);
}